// Round 16
// baseline (177.995 us; speedup 1.0000x reference)
//
#include <hip/hip_runtime.h>
#include <hip/hip_bf16.h>
#include <stdint.h>

// Problem constants
// B=128 STREAM=512 IN_CH=4 EXTRA=5 GROUPS=2 DEPTH=3 STEP=16 LENGTH=32 RNN=256 OUT=10
// C=10 SIG_C=1110 W=31 F=2220, padded K = 2240, GEMM M = 31*128 = 3968, N = 768
// gi layout (f16, COALESCED): chunk u of thread gtid at step (t,bb):
//   f16 offset = ((t*8+bb)*6 + u)*2048 + gtid*4,  u = gs*2+gtc in [0,6)
// gi VALUES pre-scaled for exp2-based gate math:
//   r,z chunks: -log2e*(gemm + b_ih + b_hh);  n chunks: 2*log2e*(gemm + b_ih)
// GEMM: in-block split-K (round-11 config, frozen).
// GRU (round 16): round-15 16-wave structure + (a) 2-step-deep gi prefetch
//   (gA/gB double buffer: step t consumes gA, shifts gB->gA, issues t+2 into
//   gB -> ~2 steps (~7000cy) of HBM-latency cover; round-15's 1-step cover
//   (~350cy) left ~500cy/step exposed vs 900cy cold-HBM latency), and
//   (b) direct f32x8 LDS loads for the fp8 A-fragments (the 32B at +0 and
//   +128 are contiguous -> no u0..u3 staging copies).
// prep: unchanged (all W_hh rows fp8 x16 in whh8).

typedef _Float16 f16;
typedef f16  f16x2 __attribute__((ext_vector_type(2)));
typedef f16  f16x4 __attribute__((ext_vector_type(4)));
typedef f16  f16x8 __attribute__((ext_vector_type(8)));
typedef float f32x2 __attribute__((ext_vector_type(2)));
typedef float f32x4 __attribute__((ext_vector_type(4)));
typedef float f32x8 __attribute__((ext_vector_type(8)));

#define ASYNC16(gp, lp) __builtin_amdgcn_global_load_lds( \
    (const __attribute__((address_space(1))) void*)(gp),  \
    (__attribute__((address_space(3))) void*)(lp), 16, 0, 0)

#define BAR_LDS() do { asm volatile("s_waitcnt lgkmcnt(0)" ::: "memory"); \
                       __builtin_amdgcn_s_barrier();                      \
                       asm volatile("" ::: "memory"); } while (0)

__device__ __forceinline__ float fexp2(float x) {
    float r; asm("v_exp_f32 %0, %1" : "=v"(r) : "v"(x)); return r;
}
__device__ __forceinline__ float frcp(float x) {
    float r; asm("v_rcp_f32 %0, %1" : "=v"(r) : "v"(x)); return r;
}

// ---------------------------------------------------------------- K0: prep
// blocks [0,840):    W_ih f32 -> f16 (pad 2220->2240), 8 elems/thread
// blocks [840,936):  W_hh f32 -> f16 (all) + fp8*16 (ALL rows), 8 elems/thread
// blocks [936,2920): signature chains, 4/block; LDS-staged coalesced row store
__global__ __launch_bounds__(256) void prep_kernel(const float* __restrict__ x,
                                                   const float* __restrict__ W_aug,
                                                   const float* __restrict__ Wih,
                                                   const float* __restrict__ Whh,
                                                   f16* __restrict__ sig16,
                                                   f16* __restrict__ wih16,
                                                   f16* __restrict__ whh16,
                                                   uint8_t* __restrict__ whh8) {
    __shared__ float dxs[4][31][10];
    __shared__ f16 srow[4][1112];                  // per-chain staging (1110 + pad)
    const int tid = threadIdx.x;
    if (blockIdx.x < 840) {
        int c = blockIdx.x * 256 + tid;          // chunk 0..215039
        int r = c / 280, kc = (c - r * 280) * 8;
        const float* src = Wih + (size_t)r * 2220 + kc;
        f16x8 o;
        if (kc + 8 <= 2220) {
            float4 v0 = *(const float4*)(src);
            float4 v1 = *(const float4*)(src + 4);
            o[0]=(f16)v0.x; o[1]=(f16)v0.y; o[2]=(f16)v0.z; o[3]=(f16)v0.w;
            o[4]=(f16)v1.x; o[5]=(f16)v1.y; o[6]=(f16)v1.z; o[7]=(f16)v1.w;
        } else {
#pragma unroll
            for (int j = 0; j < 8; j++)
                o[j] = (f16)((kc + j < 2220) ? src[j] : 0.0f);
        }
        *(f16x8*)(wih16 + (size_t)r * 2240 + kc) = o;
        return;
    }
    if (blockIdx.x < 936) {
        int c2 = ((int)blockIdx.x - 840) * 256 + tid;    // 0..24575
        int j8 = c2 * 8;
        float w[8];
        {
            float4 v0 = *(const float4*)(Whh + j8);
            float4 v1 = *(const float4*)(Whh + j8 + 4);
            w[0]=v0.x; w[1]=v0.y; w[2]=v0.z; w[3]=v0.w;
            w[4]=v1.x; w[5]=v1.y; w[6]=v1.z; w[7]=v1.w;
        }
        f16x8 o;
#pragma unroll
        for (int j = 0; j < 8; j++) o[j] = (f16)w[j];
        *(f16x8*)(whh16 + j8) = o;
        {                                        // ALL gate rows -> fp8 e4m3 (x16)
            uint32_t p01 = (uint32_t)__builtin_amdgcn_cvt_pk_fp8_f32(w[0]*16.f, w[1]*16.f, 0, false) & 0xffffu;
            uint32_t p23 = (uint32_t)__builtin_amdgcn_cvt_pk_fp8_f32(w[2]*16.f, w[3]*16.f, 0, false) & 0xffffu;
            uint32_t p45 = (uint32_t)__builtin_amdgcn_cvt_pk_fp8_f32(w[4]*16.f, w[5]*16.f, 0, false) & 0xffffu;
            uint32_t p67 = (uint32_t)__builtin_amdgcn_cvt_pk_fp8_f32(w[6]*16.f, w[7]*16.f, 0, false) & 0xffffu;
            uint2 st = make_uint2(p01 | (p23 << 16), p45 | (p67 << 16));
            *(uint2*)(whh8 + j8) = st;
        }
        return;
    }
    // ---- signature chains (block-uniform branch; __syncthreads safe)
    const int sub = tid >> 6, t64 = tid & 63;
    const int cid = ((int)blockIdx.x - 936) * 4 + sub;   // 0..7935
    const int w = cid % 31;
    const int bg = cid / 31;
    const int b = bg >> 1, g = bg & 1;
    if (t64 < 31) {
        int s = w * 16 + t64;
        const float4 x0 = *(const float4*)(x + ((size_t)b * 512 + s) * 4);
        const float4 x1 = *(const float4*)(x + ((size_t)b * 512 + s + 1) * 4);
        float d0 = x1.x - x0.x, d1 = x1.y - x0.y, d2 = x1.z - x0.z, d3 = x1.w - x0.w;
        dxs[sub][t64][0] = d0; dxs[sub][t64][1] = d1;
        dxs[sub][t64][2] = d2; dxs[sub][t64][3] = d3;
        dxs[sub][t64][4] = 1.0f / 511.0f;
#pragma unroll
        for (int e = 0; e < 5; e++) {
            const float* wa = W_aug + (g * 5 + e) * 4;
            dxs[sub][t64][5 + e] = d0 * wa[0] + d1 * wa[1] + d2 * wa[2] + d3 * wa[3];
        }
    }
    __syncthreads();
    size_t base = ((size_t)(w * 128 + b)) * 2240 + (size_t)g * 1110;
    if (t64 < 50) {
        int p0 = 2 * t64, p1 = p0 + 1;
        int i0 = p0 / 10, j0 = p0 % 10, j1 = j0 + 1;   // p0 even -> j1 <= 9
        const float* dz  = &dxs[sub][0][0];
        const float* pI  = dz + i0;
        const float* pJ0 = dz + j0;
        const float* pJ1 = dz + j1;
        float s3a[10], s3b[10];
#pragma unroll
        for (int k = 0; k < 10; k++) { s3a[k] = 0.f; s3b[k] = 0.f; }
        float s2a = 0.f, s2b = 0.f, s1 = 0.f;
        for (int l = 0; l < 31; l++) {
            const float* row = dz + l * 10;
            float di  = pI[l * 10];
            float dj0 = pJ0[l * 10];
            float dj1 = pJ1[l * 10];
            float t0 = s1 + di * (1.0f / 3.0f);
            float a0 = s2a + t0 * (0.5f * dj0);
            float a1 = s2b + t0 * (0.5f * dj1);
#pragma unroll
            for (int k = 0; k < 10; k++) {
                float dk = row[k];
                s3a[k] += a0 * dk;
                s3b[k] += a1 * dk;
            }
            float u = s1 + 0.5f * di;
            s2a += u * dj0;
            s2b += u * dj1;
            s1 += di;
        }
        *(f16x2*)&srow[sub][10 + p0] = (f16x2){(f16)s2a, (f16)s2b};
#pragma unroll
        for (int k = 0; k < 5; k++)
            *(f16x2*)&srow[sub][110 + p0 * 10 + 2 * k] =
                (f16x2){(f16)s3a[2 * k], (f16)s3a[2 * k + 1]};
#pragma unroll
        for (int k = 0; k < 5; k++)
            *(f16x2*)&srow[sub][110 + p1 * 10 + 2 * k] =
                (f16x2){(f16)s3b[2 * k], (f16)s3b[2 * k + 1]};
    } else if (t64 < 60) {
        int c = t64 - 50;
        const float* pc = &dxs[sub][0][0] + c;
        float s = 0.f;
        for (int l = 0; l < 31; l++) s += pc[l * 10];
        srow[sub][c] = (f16)s;
    }
    __syncthreads();
    for (int j = t64; j < 555; j += 64)
        *(f16x2*)(sig16 + base + 2 * j) = *(const f16x2*)&srow[sub][2 * j];
    if (g == 1 && t64 < 10)
        *(f16x2*)(sig16 + ((size_t)(w * 128 + b)) * 2240 + 2220 + 2 * t64) =
            (f16x2){(f16)0.0f, (f16)0.0f};
}

// ---------------------------------------------------------------- K2: gi = sig @ W_ih.T + biases (f16, coalesced GRU layout)
// 64x64 tile, 744 blocks x 512 thr; in-block split-K; LDS-scratch combine.
__global__ __launch_bounds__(512) void gemm_kernel(const f16* __restrict__ A,     // 3968 x 2240
                                                   const f16* __restrict__ Bw,    // 768 x 2240 f16
                                                   const float* __restrict__ bias,
                                                   const float* __restrict__ bhh,
                                                   f16* __restrict__ Cgi) {
    const int lin = blockIdx.x;          // 744 = 62 mb x 12 nc
    const int nc = lin % 12;
    const int mb = lin / 12;             // 0..61
    const int t = mb >> 1, half = mb & 1;
    __shared__ __align__(16) f16 As[2][3][64 * 32];   // 24 KB
    __shared__ __align__(16) f16 Bs[2][3][64 * 32];   // 24 KB
    __shared__ __align__(16) float sc[4][16 * 64];    // 16 KB (total 64 KB -> 2 blocks/CU)
    const int tid = threadIdx.x, lane = tid & 63, wid = tid >> 6;   // wid 0..7
    const int kh = wid >> 2, w4 = wid & 3;            // K-half, wave-in-half
    const int l16 = lane & 15, quad = lane >> 4;
    const int lrow = lane >> 2, lk = lane & 3;
    const int Nbase = nc * 64;
    const f16* gaA = A  + (size_t)(mb * 64 + w4 * 16 + lrow) * 2240 + kh * 1120 + lk * 8;
    const f16* gbB = Bw + (size_t)(Nbase + w4 * 16 + lrow) * 2240 + kh * 1120 + lk * 8;

#define GISSUE(KT, BUF) do { \
        int _k0 = (KT) * 32; \
        ASYNC16(gaA + _k0, &As[kh][BUF][(w4 * 16) * 32]); \
        ASYNC16(gbB + _k0, &Bs[kh][BUF][(w4 * 16) * 32]); } while (0)

#define GCOMPUTE(BUF) do { \
        f16x8 af, bf[4]; \
        af = *(const f16x8*)&As[kh][BUF][(w4 * 16 + l16) * 32 + quad * 8]; \
        _Pragma("unroll") \
        for (int nt = 0; nt < 4; nt++) \
            bf[nt] = *(const f16x8*)&Bs[kh][BUF][(nt * 16 + l16) * 32 + quad * 8]; \
        _Pragma("unroll") \
        for (int nt = 0; nt < 4; nt++) \
            acc[nt] = __builtin_amdgcn_mfma_f32_16x16x32_f16(af, bf[nt], acc[nt], 0, 0, 0); } while (0)

    f32x4 acc[4];
#pragma unroll
    for (int nt = 0; nt < 4; nt++) acc[nt] = (f32x4){0.f, 0.f, 0.f, 0.f};

    GISSUE(0, 0); GISSUE(1, 1);
    for (int kt = 0; kt < 33; kt++) {
        asm volatile("s_waitcnt vmcnt(2) lgkmcnt(0)\n\ts_barrier" ::: "memory");
        GISSUE(kt + 2, (kt + 2) % 3);
        GCOMPUTE(kt % 3);
    }
    asm volatile("s_waitcnt vmcnt(2) lgkmcnt(0)\n\ts_barrier" ::: "memory");
    GCOMPUTE(0);   // kt=33
    asm volatile("s_waitcnt vmcnt(0) lgkmcnt(0)\n\ts_barrier" ::: "memory");
    GCOMPUTE(1);   // kt=34

    // ---- combine K-halves via LDS scratch
    if (kh == 1) {
#pragma unroll
        for (int nt = 0; nt < 4; nt++)
#pragma unroll
            for (int rr = 0; rr < 4; rr++)
                sc[w4][(quad * 4 + rr) * 64 + nt * 16 + l16] = acc[nt][rr];
    }
    __syncthreads();
    if (kh == 0) {
        const float NEG_LOG2E = -1.4426950408889634f;
        const float TWO_LOG2E =  2.8853900817779268f;
        const int bbv = half * 4 + w4;
#pragma unroll
        for (int nt = 0; nt < 4; nt++) {
            int col = Nbase + nt * 16 + l16;
            float bvv = bias[col] + (col < 512 ? bhh[col] : 0.0f);   // fold b_hh into r,z
            float scl = (col < 512) ? NEG_LOG2E : TWO_LOG2E;
            int gs = col >> 8, hcc = col & 255;
            int gw = hcc >> 5, gtc = (hcc >> 4) & 1, gl = hcc & 15;
            int u = gs * 2 + gtc;
            int gtid = gw * 64 + quad * 16 + gl;
            size_t off = ((size_t)((t * 8 + bbv) * 6 + u)) * 2048 + (size_t)gtid * 4;
            f16x4 st;
#pragma unroll
            for (int rr = 0; rr < 4; rr++) {
                float v = acc[nt][rr] + sc[w4][(quad * 4 + rr) * 64 + nt * 16 + l16];
                st[rr] = (f16)((v + bvv) * scl);
            }
            *(f16x4*)(Cgi + off) = st;
        }
    }
#undef GISSUE
#undef GCOMPUTE
}

// ---------------------------------------------------------------- K3: GRU scan (16 waves)
// All gates K=128 fp8; wave w owns col-frag w x {r,z,n}. Weights a[0:47].
#define ACLOB48 \
  "a0","a1","a2","a3","a4","a5","a6","a7","a8","a9","a10","a11","a12","a13","a14","a15", \
  "a16","a17","a18","a19","a20","a21","a22","a23","a24","a25","a26","a27","a28","a29","a30","a31", \
  "a32","a33","a34","a35","a36","a37","a38","a39","a40","a41","a42","a43","a44","a45","a46","a47"

// one K=128 fp8 weight fragment (16 gate cols x 128 k) -> 8 AGPRs
#define LF8X(A0,A1,A2,A3,A4,A5,A6,A7, G, KF) do { \
  const uint8_t* _p = whh8 + (size_t)((G) * 256 + wid * 16 + l16) * 256 + (KF) * 128 + quad * 32; \
  f32x4 _t0 = *(const f32x4*)_p; \
  f32x4 _t1 = *(const f32x4*)(_p + 16); \
  asm volatile("v_accvgpr_write_b32 a" #A0 ", %0\n\t" \
               "v_accvgpr_write_b32 a" #A1 ", %1\n\t" \
               "v_accvgpr_write_b32 a" #A2 ", %2\n\t" \
               "v_accvgpr_write_b32 a" #A3 ", %3\n\t" \
               "v_accvgpr_write_b32 a" #A4 ", %4\n\t" \
               "v_accvgpr_write_b32 a" #A5 ", %5\n\t" \
               "v_accvgpr_write_b32 a" #A6 ", %6\n\t" \
               "v_accvgpr_write_b32 a" #A7 ", %7" \
               :: "v"(_t0[0]), "v"(_t0[1]), "v"(_t0[2]), "v"(_t0[3]), \
                  "v"(_t1[0]), "v"(_t1[1]), "v"(_t1[2]), "v"(_t1[3]) \
               : "a" #A0, "a" #A1, "a" #A2, "a" #A3, \
                 "a" #A4, "a" #A5, "a" #A6, "a" #A7); } while (0)

__global__ __launch_bounds__(1024, 4) void gru_kernel(const f16* __restrict__ gi,
                                                      const f16* __restrict__ whh16,
                                                      const uint8_t* __restrict__ whh8,
                                                      const float* __restrict__ b_hh,
                                                      const float* __restrict__ W_out,
                                                      const float* __restrict__ b_out,
                                                      float* __restrict__ out) {
    __shared__ __align__(16) f16 hbufF[16 * 280];         // final h only (head)
    __shared__ __align__(16) uint8_t hbuf8[2][16 * 272];  // fp8 h (all gates A)
    const int tid = threadIdx.x, lane = tid & 63, wid = tid >> 6;   // wid 0..15
    const int quad = lane >> 4, l16 = lane & 15;
    const int bb = blockIdx.x;

    for (int i = tid; i < 16 * 272; i += 1024) hbuf8[1][i] = 0;

    // weights: (G gate, KF k-frag) -> a[(G*2+KF)*8 .. +8)
    LF8X(0,1,2,3,4,5,6,7,         0, 0);
    LF8X(8,9,10,11,12,13,14,15,   0, 1);
    LF8X(16,17,18,19,20,21,22,23, 1, 0);
    LF8X(24,25,26,27,28,29,30,31, 1, 1);
    LF8X(32,33,34,35,36,37,38,39, 2, 0);
    LF8X(40,41,42,43,44,45,46,47, 2, 1);

    const float C2 = 2.8853900817779268f;   // 2*log2e
    const int hcx = wid * 16 + l16;         // owned gate column
    const float bhn = C2 * b_hh[512 + hcx];
    float hm[4];
#pragma unroll
    for (int rr = 0; rr < 4; rr++) hm[rr] = 0.f;

    // coalesced gi: wave owns cols wid*16..+16 -> u-chunk parity wid&1,
    // thread slot (wid>>1)*64 + quad*16 + l16; gate chunks at +gs*4096.
    const size_t lanebase = (size_t)bb * 12288 + (size_t)(wid & 1) * 2048
                          + (size_t)((wid >> 1) * 64 + quad * 16 + l16) * 4;
    // 2-step-deep gi prefetch: gA = step t, gB = step t+1
    f16x4 gA[3], gB[3];
#pragma unroll
    for (int gs = 0; gs < 3; gs++) {
        gA[gs] = *(const f16x4*)(gi + lanebase + (size_t)gs * 4096);
        gB[gs] = *(const f16x4*)(gi + (size_t)98304 + lanebase + (size_t)gs * 4096);
    }

    const f32x4 zq = (f32x4){0.f, 0.f, 0.f, 0.f};

    BAR_LDS();

    for (int t = 0; t < 31; t++) {
        const uint8_t* hb = ((t & 1) ? hbuf8[0] : hbuf8[1]) + (size_t)l16 * 272 + quad * 32;
        f32x4 aR, aZ, aN;
        // A-fragments: 32B/lane contiguous per K=128 frag (kf=0 at +0, kf=1 at +128)
        f32x8 A0f = *(const f32x8*)(hb);
        f32x8 A1f = *(const f32x8*)(hb + 128);
        __builtin_amdgcn_s_setprio(1);
        asm volatile(   // 6 x K=128 fp8 MFMA (3 independent chains x 2-deep)
            "v_mfma_f32_16x16x128_f8f6f4 %[r], %[A0], a[0:7],   %[zq]\n\t"
            "v_mfma_f32_16x16x128_f8f6f4 %[z], %[A0], a[16:23], %[zq]\n\t"
            "v_mfma_f32_16x16x128_f8f6f4 %[n], %[A0], a[32:39], %[zq]\n\t"
            "v_mfma_f32_16x16x128_f8f6f4 %[r], %[A1], a[8:15],  %[r]\n\t"
            "v_mfma_f32_16x16x128_f8f6f4 %[z], %[A1], a[24:31], %[z]\n\t"
            "v_mfma_f32_16x16x128_f8f6f4 %[n], %[A1], a[40:47], %[n]\n\t"
            "s_nop 7\n\ts_nop 7"
            : [r]"=&v"(aR), [z]"=&v"(aZ), [n]"=&v"(aN)
            : [A0]"v"(A0f), [A1]"v"(A1f), [zq]"v"(zq)
            : ACLOB48);
        __builtin_amdgcn_s_setprio(0);

        // gate math (exp2 form): all matmuls carry x16 weight scale
        uint8_t* hd8 = hbuf8[t & 1];
        const float C1N16 = -0.09016844005556021f;   // -log2e/16
        const float C2_16 =  0.18033688011112042f;   //  2*log2e/16
#pragma unroll
        for (int rr = 0; rr < 4; rr++) {
            float rg = frcp(1.f + fexp2(fmaf(C1N16, aR[rr], (float)gA[0][rr])));
            float zg = frcp(1.f + fexp2(fmaf(C1N16, aZ[rr], (float)gA[1][rr])));
            float t2 = fmaf(rg, fmaf(C2_16, aN[rr], bhn), (float)gA[2][rr]);
            float e2 = fexp2(t2);
            float ng = fmaf(-2.f, frcp(e2 + 1.f), 1.f);   // tanh
            float h  = fmaf(zg, hm[rr] - ng, ng);         // (1-z)n + z*h
            hm[rr] = h;
            int pk = __builtin_amdgcn_cvt_pk_fp8_f32(h, h, 0, false);
            hd8[(quad * 4 + rr) * 272 + hcx] = (uint8_t)pk;
            if (t == 30)
                hbufF[(quad * 4 + rr) * 280 + hcx] = (f16)h;
        }
        // shift prefetch pipeline: gA <- gB, issue t+2 into gB (2 steps cover)
        {
            int tn = (t < 29) ? t + 2 : 30;
            const f16* gsrc = gi + (size_t)tn * 98304 + lanebase;
#pragma unroll
            for (int gs = 0; gs < 3; gs++) {
                gA[gs] = gB[gs];
                gB[gs] = *(const f16x4*)(gsrc + (size_t)gs * 4096);
            }
        }
        BAR_LDS();
    }
    // output head: final h in hbufF
    if (tid < 160) {
        int r = tid / 10, oc = tid - r * 10;
        const f16* hfin = hbufF;
        float s = b_out[oc];
        for (int k = 0; k < 256; k++) s += (float)hfin[r * 280 + k] * W_out[oc * 256 + k];
        out[(bb * 16 + r) * 10 + oc] = frcp(1.f + __expf(-s));
    }
}

// ---------------------------------------------------------------- launch
extern "C" void kernel_launch(void* const* d_in, const int* in_sizes, int n_in,
                              void* d_out, int out_size, void* d_ws, size_t ws_size,
                              hipStream_t stream) {
    const float* x     = (const float*)d_in[0];
    const float* W_aug = (const float*)d_in[1];
    // d_in[2] = b_aug — cancels in dx, unused
    const float* W_ih  = (const float*)d_in[3];
    const float* W_hh  = (const float*)d_in[4];
    const float* b_ih  = (const float*)d_in[5];
    const float* b_hh  = (const float*)d_in[6];
    const float* W_out = (const float*)d_in[7];
    const float* b_out = (const float*)d_in[8];
    float* out = (float*)d_out;

    char* ws = (char*)d_ws;
    const size_t SIG_BYTES  = (size_t)3968 * 2240 * 2;           // 17,776,640
    const size_t WIH_BYTES  = (size_t)768 * 2240 * 2;            //  3,440,640
    const size_t WHH_BYTES  = (size_t)768 * 256 * 2;             //    393,216
    const size_t WHH8_BYTES = (size_t)768 * 256;                 //    196,608
    const size_t GI_BYTES   = (size_t)31 * 8 * 6 * 512 * 4 * 2;  //  6,094,848
    if (ws_size < SIG_BYTES + WIH_BYTES + WHH_BYTES + WHH8_BYTES + GI_BYTES) return;
    f16* sig16    = (f16*)ws;
    f16* wih16    = (f16*)(ws + SIG_BYTES);
    f16* whh16    = (f16*)(ws + SIG_BYTES + WIH_BYTES);
    uint8_t* whh8 = (uint8_t*)(ws + SIG_BYTES + WIH_BYTES + WHH_BYTES);
    f16* giw      = (f16*)(ws + SIG_BYTES + WIH_BYTES + WHH_BYTES + WHH8_BYTES);

    hipLaunchKernelGGL(prep_kernel, dim3(2920), dim3(256), 0, stream,
                       x, W_aug, W_ih, W_hh, sig16, wih16, whh16, whh8);
    hipLaunchKernelGGL(gemm_kernel, dim3(744), dim3(512), 0, stream,
                       sig16, wih16, b_ih, b_hh, giw);
    hipLaunchKernelGGL(gru_kernel, dim3(8), dim3(1024), 0, stream,
                       giw, whh16, whh8, b_hh, W_out, b_out, out);
}

// Round 17
// 176.074 us; speedup vs baseline: 1.0109x; 1.0109x over previous
//
#include <hip/hip_runtime.h>
#include <hip/hip_bf16.h>
#include <stdint.h>

// Problem constants
// B=128 STREAM=512 IN_CH=4 EXTRA=5 GROUPS=2 DEPTH=3 STEP=16 LENGTH=32 RNN=256 OUT=10
// C=10 SIG_C=1110 W=31 F=2220, padded K = 2240, GEMM M = 31*128 = 3968, N = 768
// gi layout (f16, COALESCED): chunk u of thread gtid at step (t,bb):
//   f16 offset = ((t*8+bb)*6 + u)*2048 + gtid*4,  u = gs*2+gtc in [0,6)
// gi VALUES pre-scaled for exp2-based gate math:
//   r,z chunks: -log2e*(gemm + b_ih + b_hh);  n chunks: 2*log2e*(gemm + b_ih)
// GEMM: in-block split-K (round-11 config, frozen).
// GRU (round 17 = round-15 revert, session best 176.4us): 16 waves, all three
//   gates via v_mfma_f32_16x16x128_f8f6f4; wave w owns col-frag w x {r,z,n};
//   1-step gi prefetch; staged u0..u3 A-fragment loads. Round-16's 2-step
//   prefetch + f32x8 direct loads REGRESSED (47.6->49.3) -> reverted.
//   Structural floor: per-step serial chain (barrier -> 512cy LDS broadcast
//   reads -> 830cy MFMA -> 700cy gate VALU) x 31 steps; no remaining theory.
// prep: unchanged (all W_hh rows fp8 x16 in whh8).

typedef _Float16 f16;
typedef f16  f16x2 __attribute__((ext_vector_type(2)));
typedef f16  f16x4 __attribute__((ext_vector_type(4)));
typedef f16  f16x8 __attribute__((ext_vector_type(8)));
typedef float f32x2 __attribute__((ext_vector_type(2)));
typedef float f32x4 __attribute__((ext_vector_type(4)));
typedef float f32x8 __attribute__((ext_vector_type(8)));

#define ASYNC16(gp, lp) __builtin_amdgcn_global_load_lds( \
    (const __attribute__((address_space(1))) void*)(gp),  \
    (__attribute__((address_space(3))) void*)(lp), 16, 0, 0)

#define BAR_LDS() do { asm volatile("s_waitcnt lgkmcnt(0)" ::: "memory"); \
                       __builtin_amdgcn_s_barrier();                      \
                       asm volatile("" ::: "memory"); } while (0)

__device__ __forceinline__ float fexp2(float x) {
    float r; asm("v_exp_f32 %0, %1" : "=v"(r) : "v"(x)); return r;
}
__device__ __forceinline__ float frcp(float x) {
    float r; asm("v_rcp_f32 %0, %1" : "=v"(r) : "v"(x)); return r;
}

// ---------------------------------------------------------------- K0: prep
// blocks [0,840):    W_ih f32 -> f16 (pad 2220->2240), 8 elems/thread
// blocks [840,936):  W_hh f32 -> f16 (all) + fp8*16 (ALL rows), 8 elems/thread
// blocks [936,2920): signature chains, 4/block; LDS-staged coalesced row store
__global__ __launch_bounds__(256) void prep_kernel(const float* __restrict__ x,
                                                   const float* __restrict__ W_aug,
                                                   const float* __restrict__ Wih,
                                                   const float* __restrict__ Whh,
                                                   f16* __restrict__ sig16,
                                                   f16* __restrict__ wih16,
                                                   f16* __restrict__ whh16,
                                                   uint8_t* __restrict__ whh8) {
    __shared__ float dxs[4][31][10];
    __shared__ f16 srow[4][1112];                  // per-chain staging (1110 + pad)
    const int tid = threadIdx.x;
    if (blockIdx.x < 840) {
        int c = blockIdx.x * 256 + tid;          // chunk 0..215039
        int r = c / 280, kc = (c - r * 280) * 8;
        const float* src = Wih + (size_t)r * 2220 + kc;
        f16x8 o;
        if (kc + 8 <= 2220) {
            float4 v0 = *(const float4*)(src);
            float4 v1 = *(const float4*)(src + 4);
            o[0]=(f16)v0.x; o[1]=(f16)v0.y; o[2]=(f16)v0.z; o[3]=(f16)v0.w;
            o[4]=(f16)v1.x; o[5]=(f16)v1.y; o[6]=(f16)v1.z; o[7]=(f16)v1.w;
        } else {
#pragma unroll
            for (int j = 0; j < 8; j++)
                o[j] = (f16)((kc + j < 2220) ? src[j] : 0.0f);
        }
        *(f16x8*)(wih16 + (size_t)r * 2240 + kc) = o;
        return;
    }
    if (blockIdx.x < 936) {
        int c2 = ((int)blockIdx.x - 840) * 256 + tid;    // 0..24575
        int j8 = c2 * 8;
        float w[8];
        {
            float4 v0 = *(const float4*)(Whh + j8);
            float4 v1 = *(const float4*)(Whh + j8 + 4);
            w[0]=v0.x; w[1]=v0.y; w[2]=v0.z; w[3]=v0.w;
            w[4]=v1.x; w[5]=v1.y; w[6]=v1.z; w[7]=v1.w;
        }
        f16x8 o;
#pragma unroll
        for (int j = 0; j < 8; j++) o[j] = (f16)w[j];
        *(f16x8*)(whh16 + j8) = o;
        {                                        // ALL gate rows -> fp8 e4m3 (x16)
            uint32_t p01 = (uint32_t)__builtin_amdgcn_cvt_pk_fp8_f32(w[0]*16.f, w[1]*16.f, 0, false) & 0xffffu;
            uint32_t p23 = (uint32_t)__builtin_amdgcn_cvt_pk_fp8_f32(w[2]*16.f, w[3]*16.f, 0, false) & 0xffffu;
            uint32_t p45 = (uint32_t)__builtin_amdgcn_cvt_pk_fp8_f32(w[4]*16.f, w[5]*16.f, 0, false) & 0xffffu;
            uint32_t p67 = (uint32_t)__builtin_amdgcn_cvt_pk_fp8_f32(w[6]*16.f, w[7]*16.f, 0, false) & 0xffffu;
            uint2 st = make_uint2(p01 | (p23 << 16), p45 | (p67 << 16));
            *(uint2*)(whh8 + j8) = st;
        }
        return;
    }
    // ---- signature chains (block-uniform branch; __syncthreads safe)
    const int sub = tid >> 6, t64 = tid & 63;
    const int cid = ((int)blockIdx.x - 936) * 4 + sub;   // 0..7935
    const int w = cid % 31;
    const int bg = cid / 31;
    const int b = bg >> 1, g = bg & 1;
    if (t64 < 31) {
        int s = w * 16 + t64;
        const float4 x0 = *(const float4*)(x + ((size_t)b * 512 + s) * 4);
        const float4 x1 = *(const float4*)(x + ((size_t)b * 512 + s + 1) * 4);
        float d0 = x1.x - x0.x, d1 = x1.y - x0.y, d2 = x1.z - x0.z, d3 = x1.w - x0.w;
        dxs[sub][t64][0] = d0; dxs[sub][t64][1] = d1;
        dxs[sub][t64][2] = d2; dxs[sub][t64][3] = d3;
        dxs[sub][t64][4] = 1.0f / 511.0f;
#pragma unroll
        for (int e = 0; e < 5; e++) {
            const float* wa = W_aug + (g * 5 + e) * 4;
            dxs[sub][t64][5 + e] = d0 * wa[0] + d1 * wa[1] + d2 * wa[2] + d3 * wa[3];
        }
    }
    __syncthreads();
    size_t base = ((size_t)(w * 128 + b)) * 2240 + (size_t)g * 1110;
    if (t64 < 50) {
        int p0 = 2 * t64, p1 = p0 + 1;
        int i0 = p0 / 10, j0 = p0 % 10, j1 = j0 + 1;   // p0 even -> j1 <= 9
        const float* dz  = &dxs[sub][0][0];
        const float* pI  = dz + i0;
        const float* pJ0 = dz + j0;
        const float* pJ1 = dz + j1;
        float s3a[10], s3b[10];
#pragma unroll
        for (int k = 0; k < 10; k++) { s3a[k] = 0.f; s3b[k] = 0.f; }
        float s2a = 0.f, s2b = 0.f, s1 = 0.f;
        for (int l = 0; l < 31; l++) {
            const float* row = dz + l * 10;
            float di  = pI[l * 10];
            float dj0 = pJ0[l * 10];
            float dj1 = pJ1[l * 10];
            float t0 = s1 + di * (1.0f / 3.0f);
            float a0 = s2a + t0 * (0.5f * dj0);
            float a1 = s2b + t0 * (0.5f * dj1);
#pragma unroll
            for (int k = 0; k < 10; k++) {
                float dk = row[k];
                s3a[k] += a0 * dk;
                s3b[k] += a1 * dk;
            }
            float u = s1 + 0.5f * di;
            s2a += u * dj0;
            s2b += u * dj1;
            s1 += di;
        }
        *(f16x2*)&srow[sub][10 + p0] = (f16x2){(f16)s2a, (f16)s2b};
#pragma unroll
        for (int k = 0; k < 5; k++)
            *(f16x2*)&srow[sub][110 + p0 * 10 + 2 * k] =
                (f16x2){(f16)s3a[2 * k], (f16)s3a[2 * k + 1]};
#pragma unroll
        for (int k = 0; k < 5; k++)
            *(f16x2*)&srow[sub][110 + p1 * 10 + 2 * k] =
                (f16x2){(f16)s3b[2 * k], (f16)s3b[2 * k + 1]};
    } else if (t64 < 60) {
        int c = t64 - 50;
        const float* pc = &dxs[sub][0][0] + c;
        float s = 0.f;
        for (int l = 0; l < 31; l++) s += pc[l * 10];
        srow[sub][c] = (f16)s;
    }
    __syncthreads();
    for (int j = t64; j < 555; j += 64)
        *(f16x2*)(sig16 + base + 2 * j) = *(const f16x2*)&srow[sub][2 * j];
    if (g == 1 && t64 < 10)
        *(f16x2*)(sig16 + ((size_t)(w * 128 + b)) * 2240 + 2220 + 2 * t64) =
            (f16x2){(f16)0.0f, (f16)0.0f};
}

// ---------------------------------------------------------------- K2: gi = sig @ W_ih.T + biases (f16, coalesced GRU layout)
// 64x64 tile, 744 blocks x 512 thr; in-block split-K; LDS-scratch combine.
__global__ __launch_bounds__(512) void gemm_kernel(const f16* __restrict__ A,     // 3968 x 2240
                                                   const f16* __restrict__ Bw,    // 768 x 2240 f16
                                                   const float* __restrict__ bias,
                                                   const float* __restrict__ bhh,
                                                   f16* __restrict__ Cgi) {
    const int lin = blockIdx.x;          // 744 = 62 mb x 12 nc
    const int nc = lin % 12;
    const int mb = lin / 12;             // 0..61
    const int t = mb >> 1, half = mb & 1;
    __shared__ __align__(16) f16 As[2][3][64 * 32];   // 24 KB
    __shared__ __align__(16) f16 Bs[2][3][64 * 32];   // 24 KB
    __shared__ __align__(16) float sc[4][16 * 64];    // 16 KB (total 64 KB -> 2 blocks/CU)
    const int tid = threadIdx.x, lane = tid & 63, wid = tid >> 6;   // wid 0..7
    const int kh = wid >> 2, w4 = wid & 3;            // K-half, wave-in-half
    const int l16 = lane & 15, quad = lane >> 4;
    const int lrow = lane >> 2, lk = lane & 3;
    const int Nbase = nc * 64;
    const f16* gaA = A  + (size_t)(mb * 64 + w4 * 16 + lrow) * 2240 + kh * 1120 + lk * 8;
    const f16* gbB = Bw + (size_t)(Nbase + w4 * 16 + lrow) * 2240 + kh * 1120 + lk * 8;

#define GISSUE(KT, BUF) do { \
        int _k0 = (KT) * 32; \
        ASYNC16(gaA + _k0, &As[kh][BUF][(w4 * 16) * 32]); \
        ASYNC16(gbB + _k0, &Bs[kh][BUF][(w4 * 16) * 32]); } while (0)

#define GCOMPUTE(BUF) do { \
        f16x8 af, bf[4]; \
        af = *(const f16x8*)&As[kh][BUF][(w4 * 16 + l16) * 32 + quad * 8]; \
        _Pragma("unroll") \
        for (int nt = 0; nt < 4; nt++) \
            bf[nt] = *(const f16x8*)&Bs[kh][BUF][(nt * 16 + l16) * 32 + quad * 8]; \
        _Pragma("unroll") \
        for (int nt = 0; nt < 4; nt++) \
            acc[nt] = __builtin_amdgcn_mfma_f32_16x16x32_f16(af, bf[nt], acc[nt], 0, 0, 0); } while (0)

    f32x4 acc[4];
#pragma unroll
    for (int nt = 0; nt < 4; nt++) acc[nt] = (f32x4){0.f, 0.f, 0.f, 0.f};

    GISSUE(0, 0); GISSUE(1, 1);
    for (int kt = 0; kt < 33; kt++) {
        asm volatile("s_waitcnt vmcnt(2) lgkmcnt(0)\n\ts_barrier" ::: "memory");
        GISSUE(kt + 2, (kt + 2) % 3);
        GCOMPUTE(kt % 3);
    }
    asm volatile("s_waitcnt vmcnt(2) lgkmcnt(0)\n\ts_barrier" ::: "memory");
    GCOMPUTE(0);   // kt=33
    asm volatile("s_waitcnt vmcnt(0) lgkmcnt(0)\n\ts_barrier" ::: "memory");
    GCOMPUTE(1);   // kt=34

    // ---- combine K-halves via LDS scratch
    if (kh == 1) {
#pragma unroll
        for (int nt = 0; nt < 4; nt++)
#pragma unroll
            for (int rr = 0; rr < 4; rr++)
                sc[w4][(quad * 4 + rr) * 64 + nt * 16 + l16] = acc[nt][rr];
    }
    __syncthreads();
    if (kh == 0) {
        const float NEG_LOG2E = -1.4426950408889634f;
        const float TWO_LOG2E =  2.8853900817779268f;
        const int bbv = half * 4 + w4;
#pragma unroll
        for (int nt = 0; nt < 4; nt++) {
            int col = Nbase + nt * 16 + l16;
            float bvv = bias[col] + (col < 512 ? bhh[col] : 0.0f);   // fold b_hh into r,z
            float scl = (col < 512) ? NEG_LOG2E : TWO_LOG2E;
            int gs = col >> 8, hcc = col & 255;
            int gw = hcc >> 5, gtc = (hcc >> 4) & 1, gl = hcc & 15;
            int u = gs * 2 + gtc;
            int gtid = gw * 64 + quad * 16 + gl;
            size_t off = ((size_t)((t * 8 + bbv) * 6 + u)) * 2048 + (size_t)gtid * 4;
            f16x4 st;
#pragma unroll
            for (int rr = 0; rr < 4; rr++) {
                float v = acc[nt][rr] + sc[w4][(quad * 4 + rr) * 64 + nt * 16 + l16];
                st[rr] = (f16)((v + bvv) * scl);
            }
            *(f16x4*)(Cgi + off) = st;
        }
    }
#undef GISSUE
#undef GCOMPUTE
}

// ---------------------------------------------------------------- K3: GRU scan (16 waves)
// All gates K=128 fp8; wave w owns col-frag w x {r,z,n}. Weights a[0:47].
#define ACLOB48 \
  "a0","a1","a2","a3","a4","a5","a6","a7","a8","a9","a10","a11","a12","a13","a14","a15", \
  "a16","a17","a18","a19","a20","a21","a22","a23","a24","a25","a26","a27","a28","a29","a30","a31", \
  "a32","a33","a34","a35","a36","a37","a38","a39","a40","a41","a42","a43","a44","a45","a46","a47"

// one K=128 fp8 weight fragment (16 gate cols x 128 k) -> 8 AGPRs
#define LF8X(A0,A1,A2,A3,A4,A5,A6,A7, G, KF) do { \
  const uint8_t* _p = whh8 + (size_t)((G) * 256 + wid * 16 + l16) * 256 + (KF) * 128 + quad * 32; \
  f32x4 _t0 = *(const f32x4*)_p; \
  f32x4 _t1 = *(const f32x4*)(_p + 16); \
  asm volatile("v_accvgpr_write_b32 a" #A0 ", %0\n\t" \
               "v_accvgpr_write_b32 a" #A1 ", %1\n\t" \
               "v_accvgpr_write_b32 a" #A2 ", %2\n\t" \
               "v_accvgpr_write_b32 a" #A3 ", %3\n\t" \
               "v_accvgpr_write_b32 a" #A4 ", %4\n\t" \
               "v_accvgpr_write_b32 a" #A5 ", %5\n\t" \
               "v_accvgpr_write_b32 a" #A6 ", %6\n\t" \
               "v_accvgpr_write_b32 a" #A7 ", %7" \
               :: "v"(_t0[0]), "v"(_t0[1]), "v"(_t0[2]), "v"(_t0[3]), \
                  "v"(_t1[0]), "v"(_t1[1]), "v"(_t1[2]), "v"(_t1[3]) \
               : "a" #A0, "a" #A1, "a" #A2, "a" #A3, \
                 "a" #A4, "a" #A5, "a" #A6, "a" #A7); } while (0)

__global__ __launch_bounds__(1024, 4) void gru_kernel(const f16* __restrict__ gi,
                                                      const f16* __restrict__ whh16,
                                                      const uint8_t* __restrict__ whh8,
                                                      const float* __restrict__ b_hh,
                                                      const float* __restrict__ W_out,
                                                      const float* __restrict__ b_out,
                                                      float* __restrict__ out) {
    __shared__ __align__(16) f16 hbufF[16 * 280];         // final h only (head)
    __shared__ __align__(16) uint8_t hbuf8[2][16 * 272];  // fp8 h (all gates A)
    const int tid = threadIdx.x, lane = tid & 63, wid = tid >> 6;   // wid 0..15
    const int quad = lane >> 4, l16 = lane & 15;
    const int bb = blockIdx.x;

    for (int i = tid; i < 16 * 272; i += 1024) hbuf8[1][i] = 0;

    // weights: (G gate, KF k-frag) -> a[(G*2+KF)*8 .. +8)
    LF8X(0,1,2,3,4,5,6,7,         0, 0);
    LF8X(8,9,10,11,12,13,14,15,   0, 1);
    LF8X(16,17,18,19,20,21,22,23, 1, 0);
    LF8X(24,25,26,27,28,29,30,31, 1, 1);
    LF8X(32,33,34,35,36,37,38,39, 2, 0);
    LF8X(40,41,42,43,44,45,46,47, 2, 1);

    const float C2 = 2.8853900817779268f;   // 2*log2e
    const int hcx = wid * 16 + l16;         // owned gate column
    const float bhn = C2 * b_hh[512 + hcx];
    float hm[4];
#pragma unroll
    for (int rr = 0; rr < 4; rr++) hm[rr] = 0.f;

    // coalesced gi: wave owns cols wid*16..+16 -> u-chunk parity wid&1,
    // thread slot (wid>>1)*64 + quad*16 + l16; gate chunks at +gs*4096.
    const size_t lanebase = (size_t)bb * 12288 + (size_t)(wid & 1) * 2048
                          + (size_t)((wid >> 1) * 64 + quad * 16 + l16) * 4;
    f16x4 gcur[3];
#pragma unroll
    for (int gs = 0; gs < 3; gs++)
        gcur[gs] = *(const f16x4*)(gi + lanebase + (size_t)gs * 4096);

    const f32x4 zq = (f32x4){0.f, 0.f, 0.f, 0.f};

    BAR_LDS();

    for (int t = 0; t < 31; t++) {
        const uint8_t* hb = ((t & 1) ? hbuf8[0] : hbuf8[1]) + (size_t)l16 * 272 + quad * 32;
        f32x4 aR, aZ, aN;
        // A-fragments: 32B/lane per K=128 frag (kf=0 at +0, kf=1 at +128)
        f32x4 u0 = *(const f32x4*)(hb);
        f32x4 u1 = *(const f32x4*)(hb + 16);
        f32x4 u2 = *(const f32x4*)(hb + 128);
        f32x4 u3 = *(const f32x4*)(hb + 144);
        f32x8 A0f, A1f;
        A0f[0]=u0[0]; A0f[1]=u0[1]; A0f[2]=u0[2]; A0f[3]=u0[3];
        A0f[4]=u1[0]; A0f[5]=u1[1]; A0f[6]=u1[2]; A0f[7]=u1[3];
        A1f[0]=u2[0]; A1f[1]=u2[1]; A1f[2]=u2[2]; A1f[3]=u2[3];
        A1f[4]=u3[0]; A1f[5]=u3[1]; A1f[6]=u3[2]; A1f[7]=u3[3];
        __builtin_amdgcn_s_setprio(1);
        asm volatile(   // 6 x K=128 fp8 MFMA (3 independent chains x 2-deep)
            "v_mfma_f32_16x16x128_f8f6f4 %[r], %[A0], a[0:7],   %[zq]\n\t"
            "v_mfma_f32_16x16x128_f8f6f4 %[z], %[A0], a[16:23], %[zq]\n\t"
            "v_mfma_f32_16x16x128_f8f6f4 %[n], %[A0], a[32:39], %[zq]\n\t"
            "v_mfma_f32_16x16x128_f8f6f4 %[r], %[A1], a[8:15],  %[r]\n\t"
            "v_mfma_f32_16x16x128_f8f6f4 %[z], %[A1], a[24:31], %[z]\n\t"
            "v_mfma_f32_16x16x128_f8f6f4 %[n], %[A1], a[40:47], %[n]\n\t"
            "s_nop 7\n\ts_nop 7"
            : [r]"=&v"(aR), [z]"=&v"(aZ), [n]"=&v"(aN)
            : [A0]"v"(A0f), [A1]"v"(A1f), [zq]"v"(zq)
            : ACLOB48);
        __builtin_amdgcn_s_setprio(0);

        // gate math (exp2 form): all matmuls carry x16 weight scale
        uint8_t* hd8 = hbuf8[t & 1];
        const float C1N16 = -0.09016844005556021f;   // -log2e/16
        const float C2_16 =  0.18033688011112042f;   //  2*log2e/16
#pragma unroll
        for (int rr = 0; rr < 4; rr++) {
            float rg = frcp(1.f + fexp2(fmaf(C1N16, aR[rr], (float)gcur[0][rr])));
            float zg = frcp(1.f + fexp2(fmaf(C1N16, aZ[rr], (float)gcur[1][rr])));
            float t2 = fmaf(rg, fmaf(C2_16, aN[rr], bhn), (float)gcur[2][rr]);
            float e2 = fexp2(t2);
            float ng = fmaf(-2.f, frcp(e2 + 1.f), 1.f);   // tanh
            float h  = fmaf(zg, hm[rr] - ng, ng);         // (1-z)n + z*h
            hm[rr] = h;
            int pk = __builtin_amdgcn_cvt_pk_fp8_f32(h, h, 0, false);
            hd8[(quad * 4 + rr) * 272 + hcx] = (uint8_t)pk;
            if (t == 30)
                hbufF[(quad * 4 + rr) * 280 + hcx] = (f16)h;
        }
        // prefetch gi for t+1 (registers; survives lgkm-only barrier)
        {
            int tn = (t < 30) ? t + 1 : 30;
            const f16* gsrc = gi + (size_t)tn * 98304 + lanebase;
#pragma unroll
            for (int gs = 0; gs < 3; gs++)
                gcur[gs] = *(const f16x4*)(gsrc + (size_t)gs * 4096);
        }
        BAR_LDS();
    }
    // output head: final h in hbufF
    if (tid < 160) {
        int r = tid / 10, oc = tid - r * 10;
        const f16* hfin = hbufF;
        float s = b_out[oc];
        for (int k = 0; k < 256; k++) s += (float)hfin[r * 280 + k] * W_out[oc * 256 + k];
        out[(bb * 16 + r) * 10 + oc] = frcp(1.f + __expf(-s));
    }
}

// ---------------------------------------------------------------- launch
extern "C" void kernel_launch(void* const* d_in, const int* in_sizes, int n_in,
                              void* d_out, int out_size, void* d_ws, size_t ws_size,
                              hipStream_t stream) {
    const float* x     = (const float*)d_in[0];
    const float* W_aug = (const float*)d_in[1];
    // d_in[2] = b_aug — cancels in dx, unused
    const float* W_ih  = (const float*)d_in[3];
    const float* W_hh  = (const float*)d_in[4];
    const float* b_ih  = (const float*)d_in[5];
    const float* b_hh  = (const float*)d_in[6];
    const float* W_out = (const float*)d_in[7];
    const float* b_out = (const float*)d_in[8];
    float* out = (float*)d_out;

    char* ws = (char*)d_ws;
    const size_t SIG_BYTES  = (size_t)3968 * 2240 * 2;           // 17,776,640
    const size_t WIH_BYTES  = (size_t)768 * 2240 * 2;            //  3,440,640
    const size_t WHH_BYTES  = (size_t)768 * 256 * 2;             //    393,216
    const size_t WHH8_BYTES = (size_t)768 * 256;                 //    196,608
    const size_t GI_BYTES   = (size_t)31 * 8 * 6 * 512 * 4 * 2;  //  6,094,848
    if (ws_size < SIG_BYTES + WIH_BYTES + WHH_BYTES + WHH8_BYTES + GI_BYTES) return;
    f16* sig16    = (f16*)ws;
    f16* wih16    = (f16*)(ws + SIG_BYTES);
    f16* whh16    = (f16*)(ws + SIG_BYTES + WIH_BYTES);
    uint8_t* whh8 = (uint8_t*)(ws + SIG_BYTES + WIH_BYTES + WHH_BYTES);
    f16* giw      = (f16*)(ws + SIG_BYTES + WIH_BYTES + WHH_BYTES + WHH8_BYTES);

    hipLaunchKernelGGL(prep_kernel, dim3(2920), dim3(256), 0, stream,
                       x, W_aug, W_ih, W_hh, sig16, wih16, whh16, whh8);
    hipLaunchKernelGGL(gemm_kernel, dim3(744), dim3(512), 0, stream,
                       sig16, wih16, b_ih, b_hh, giw);
    hipLaunchKernelGGL(gru_kernel, dim3(8), dim3(1024), 0, stream,
                       giw, whh16, whh8, b_hh, W_out, b_out, out);
}